// Round 5
// baseline (742.407 us; speedup 1.0000x reference)
//
#include <hip/hip_runtime.h>
#include <math.h>

#define EPSV 1e-5f

// Shapes (fixed): B=64, C=2048, H=24, W=8 -> L=192, M=B*L=12288
// D_in2=384, Dssm=192, N=16, R=6

typedef __attribute__((ext_vector_type(8))) __bf16 bf16x8;
typedef __attribute__((ext_vector_type(4))) float f32x4;

__device__ __forceinline__ ushort f2bf(float f) {
  union { float f; unsigned u; } v; v.f = f;
  const unsigned r = v.u + 0x7fffu + ((v.u >> 16) & 1u);  // RNE
  return (ushort)(r >> 16);
}

// async 16B/lane global->LDS: LDS dest = wave-uniform base + lane*16
#define GLOAD16(G, L) __builtin_amdgcn_global_load_lds( \
    (__attribute__((address_space(1))) void*)(G), \
    (__attribute__((address_space(3))) void*)(L), 16, 0, 0)

// ---------------- fp32 -> bf16 convert ----------------
__global__ __launch_bounds__(256) void cvt_kernel(
    const float* __restrict__ s, ushort* __restrict__ d, int n)
{
  const int i = (blockIdx.x * 256 + threadIdx.x) * 4;
  if (i + 3 < n) {
    const float4 v = *(const float4*)(s + i);
    ushort4 o;
    o.x = f2bf(v.x); o.y = f2bf(v.y); o.z = f2bf(v.z); o.w = f2bf(v.w);
    *(ushort4*)(d + i) = o;
  }
}

// ---------------- transpose out_w (2048x192) -> bf16 out_wT (256x2048, pad 0) --
__global__ __launch_bounds__(256) void transpose_w(
    const float* __restrict__ w, ushort* __restrict__ wT)
{
  __shared__ float t[64][65];
  const int c0 = blockIdx.x * 64, d0 = blockIdx.y * 64;
  const int tl = threadIdx.x & 63, tg = threadIdx.x >> 6;
#pragma unroll
  for (int r = 0; r < 16; ++r) {
    const int c = r * 4 + tg;
    t[c][tl] = w[(size_t)(c0 + c) * 192 + d0 + tl];
  }
  __syncthreads();
#pragma unroll
  for (int r = 0; r < 16; ++r) {
    const int d = r * 4 + tg;
    wT[(size_t)(d0 + d) * 2048 + c0 + tl] = f2bf(t[tl][d]);
  }
}

// ---------------- LN stats: coalesced partial sums + atomics ----------------
__global__ __launch_bounds__(256) void ln_stats(
    const float* __restrict__ feat, float* __restrict__ sums)
{
  const int b = blockIdx.x, c0 = blockIdx.y * 128;
  const int l = threadIdx.x;
  if (l >= 192) return;
  const float* p = feat + ((size_t)b * 2048 + c0) * 192 + l;
  float s = 0.f, sq = 0.f;
  for (int c = 0; c < 128; ++c) { const float v = p[(size_t)c * 192]; s += v; sq = fmaf(v, v, sq); }
  atomicAdd(&sums[(b * 192 + l) * 2], s);
  atomicAdd(&sums[(b * 192 + l) * 2 + 1], sq);
}

// ---------------- LN apply + transpose -> bf16 fm (B*L, C) ----------------
__global__ __launch_bounds__(256) void ln_apply(
    const float* __restrict__ feat, const float* __restrict__ sums,
    const float* __restrict__ lnw, const float* __restrict__ lnb,
    ushort* __restrict__ fm)
{
  __shared__ float tile[64][65];
  __shared__ float smu[64], srs[64];
  const int b = blockIdx.x, c0 = blockIdx.y * 64, l0 = blockIdx.z * 64;
  const int tl = threadIdx.x & 63, tg = threadIdx.x >> 6;
#pragma unroll
  for (int r = 0; r < 16; ++r) {
    const int c = r * 4 + tg;
    tile[c][tl] = feat[((size_t)b * 2048 + c0 + c) * 192 + l0 + tl];
  }
  if (threadIdx.x < 64) {
    const float s  = sums[(b * 192 + l0 + threadIdx.x) * 2];
    const float sq = sums[(b * 192 + l0 + threadIdx.x) * 2 + 1];
    const float mu = s * (1.f / 2048.f);
    smu[threadIdx.x] = mu;
    srs[threadIdx.x] = rsqrtf(sq * (1.f / 2048.f) - mu * mu + EPSV);
  }
  __syncthreads();
  const float w = lnw[c0 + tl], bb = lnb[c0 + tl];
#pragma unroll
  for (int r = 0; r < 16; ++r) {
    const int ll = r * 4 + tg;
    fm[((size_t)(b * 192 + l0 + ll)) * 2048 + c0 + tl] =
        f2bf((tile[tl][ll] - smu[ll]) * srs[ll] * w + bb);
  }
}

// ---------------- MFMA K-phase: 128x128 tile, BK=32, 16x16x32 bf16 ----------
__device__ __forceinline__ void mfma_phase(
    const ushort* __restrict__ Ag, int lda,
    const ushort* __restrict__ Bg, int ldb, int kbeg, int kend,
    int bm, int bn, int tid, ushort* As, ushort* Bs, f32x4 acc[4][4])
{
  const int lane = tid & 63, wave = tid >> 6;
  const int wm = (wave & 1) << 6, wn = (wave >> 1) << 6;
  const int fr = lane & 15, q = lane >> 4;
  const int r0 = tid >> 2, kc = (tid & 3) << 3;   // staging row / k-chunk
  const int lb = (tid & 192) * 8;                 // wave-uniform LDS base (ushorts)
  for (int k0 = kbeg; k0 < kend; k0 += 32) {
    __syncthreads();
    GLOAD16(Ag + (size_t)(bm + r0) * lda + k0 + kc,      As + lb);
    GLOAD16(Ag + (size_t)(bm + 64 + r0) * lda + k0 + kc, As + 2048 + lb);
    GLOAD16(Bg + (size_t)(bn + r0) * ldb + k0 + kc,      Bs + lb);
    GLOAD16(Bg + (size_t)(bn + 64 + r0) * ldb + k0 + kc, Bs + 2048 + lb);
    __syncthreads();
    bf16x8 af[4], bfr[4];
#pragma unroll
    for (int i = 0; i < 4; ++i) {
      af[i]  = *(const bf16x8*)&As[(wm + i * 16 + fr) * 32 + q * 8];
      bfr[i] = *(const bf16x8*)&Bs[(wn + i * 16 + fr) * 32 + q * 8];
    }
#pragma unroll
    for (int i = 0; i < 4; ++i)
#pragma unroll
      for (int j = 0; j < 4; ++j)
        acc[i][j] = __builtin_amdgcn_mfma_f32_16x16x32_bf16(af[i], bfr[j], acc[i][j], 0, 0, 0);
  }
}

// MODE 0: split-K=4, atomicAdd fp32 into out (xz, ldc=384). XCD-swizzled.
// MODE 1: out = relu((A1*B1^T + A2*B2^T)*scale(p0) + shift(p1)), transposed. XCD-swizzled.
// MODE 2: split-K=8, atomicAdd fp32 into out (W2f, ldc=192, n<192).
template<int MODE>
__global__ __launch_bounds__(256) void mfma_gemm(
    const ushort* __restrict__ A1, const ushort* __restrict__ B1,
    const ushort* __restrict__ A2, const ushort* __restrict__ B2,
    const float* __restrict__ p0, const float* __restrict__ p1,
    float* __restrict__ out)
{
  __shared__ ushort As[4096], Bs[4096];
  const int tid = threadIdx.x;
  const int bidx = blockIdx.x;
  int bm, bn;
  f32x4 acc[4][4];
#pragma unroll
  for (int i = 0; i < 4; ++i)
#pragma unroll
    for (int j = 0; j < 4; ++j) acc[i][j] = (f32x4)(0.f);

  if (MODE == 0) {
    // 1152 blocks: xcd(8) x [bm_local(12) x bn(3) x kz(4)]
    const int xcd = bidx & 7, j = bidx >> 3;
    bm = (xcd * 12 + j % 12) * 128;
    const int t = j / 12;
    bn = (t % 3) * 128;
    const int kz = t / 3;
    mfma_phase(A1, 2048, B1, 2048, kz * 512, kz * 512 + 512, bm, bn, tid, As, Bs, acc);
  } else if (MODE == 1) {
    // 1536 blocks: xcd(8) x [bm_local(12) x bn(16)]
    const int xcd = bidx & 7, j = bidx >> 3;
    bm = (xcd * 12 + j % 12) * 128;
    bn = (j / 12) * 128;
    mfma_phase(A1, 2048, B1, 2048, 0, 2048, bm, bn, tid, As, Bs, acc);
    mfma_phase(A2, 192, B2, 192, 0, 192, bm, bn, tid, As, Bs, acc);
  } else {
    // 256 blocks: bn(2) x bm(16) x kz(8)
    bn = (bidx & 1) * 128;
    const int r = bidx >> 1;
    bm = (r & 15) * 128;
    const int kz = r >> 4;
    mfma_phase(A1, 2048, B1, 2048, kz * 256, kz * 256 + 256, bm, bn, tid, As, Bs, acc);
  }

  const int lane = tid & 63, wave = tid >> 6;
  const int wm = (wave & 1) << 6, wn = (wave >> 1) << 6;
  const int fr = lane & 15, q = lane >> 4;
  if (MODE == 0) {
#pragma unroll
    for (int mi = 0; mi < 4; ++mi) {
      const int m0 = bm + wm + mi * 16 + q * 4;
#pragma unroll
      for (int ni = 0; ni < 4; ++ni) {
        const int n = bn + wn + ni * 16 + fr;
#pragma unroll
        for (int r = 0; r < 4; ++r)
          atomicAdd(&out[(size_t)(m0 + r) * 384 + n], acc[mi][ni][r]);
      }
    }
  } else if (MODE == 1) {
#pragma unroll
    for (int mi = 0; mi < 4; ++mi) {
      const int m0 = bm + wm + mi * 16 + q * 4;
      const int b = m0 / 192, l0 = m0 - b * 192;   // quad never straddles b
#pragma unroll
      for (int ni = 0; ni < 4; ++ni) {
        const int n = bn + wn + ni * 16 + fr;
        const float sc = p0[n], sh = p1[n];
        float4 o;
        o.x = fmaxf(fmaf(acc[mi][ni][0], sc, sh), 0.f);
        o.y = fmaxf(fmaf(acc[mi][ni][1], sc, sh), 0.f);
        o.z = fmaxf(fmaf(acc[mi][ni][2], sc, sh), 0.f);
        o.w = fmaxf(fmaf(acc[mi][ni][3], sc, sh), 0.f);
        *(float4*)(out + ((size_t)b * 2048 + n) * 192 + l0) = o;
      }
    }
  } else {
#pragma unroll
    for (int mi = 0; mi < 4; ++mi) {
      const int m0 = bm + wm + mi * 16 + q * 4;
#pragma unroll
      for (int ni = 0; ni < 4; ++ni) {
        const int n = bn + wn + ni * 16 + fr;
        if (n < 192) {
#pragma unroll
          for (int r = 0; r < 4; ++r)
            atomicAdd(&out[(size_t)(m0 + r) * 192 + n], acc[mi][ni][r]);
        }
      }
    }
  }
}

// ---------------- x_proj + dt (4 rows/block; xz is bias-less, add in_b) ------
__global__ __launch_bounds__(256) void xproj_kernel(
    const float* __restrict__ xz, const float* __restrict__ in_b,
    const float* __restrict__ xpw, const float* __restrict__ dtw,
    float* __restrict__ dts, float* __restrict__ Bsb, float* __restrict__ Csb)
{
  __shared__ float xrow[4][192];
  __shared__ float xdbl[4][38];
  const int tid = threadIdx.x;
  const int r = tid >> 6, lane = tid & 63;
  const int m = blockIdx.x * 4 + r;
  const float* src = xz + (size_t)m * 384;
#pragma unroll
  for (int i = 0; i < 3; ++i) {
    const int c = lane + i * 64;
    xrow[r][c] = src[c] + in_b[c];
  }
  __syncthreads();
  if (lane < 38) {
    float a = 0.f;
    const float* wr = xpw + lane * 192;
    for (int d = 0; d < 192; ++d) a = fmaf(xrow[r][d], wr[d], a);
    xdbl[r][lane] = a;
  }
  __syncthreads();
  if (lane < 16) Bsb[(size_t)m * 16 + lane] = xdbl[r][6 + lane];
  else if (lane < 32) Csb[(size_t)m * 16 + (lane - 16)] = xdbl[r][22 + (lane - 16)];
#pragma unroll
  for (int i = 0; i < 3; ++i) {
    const int d = lane + i * 64;
    const float* w = dtw + d * 6;
    float a = xdbl[r][0] * w[0] + xdbl[r][1] * w[1] + xdbl[r][2] * w[2]
            + xdbl[r][3] * w[3] + xdbl[r][4] * w[4] + xdbl[r][5] * w[5];
    dts[(size_t)m * 192 + d] = (a > 20.f) ? a : log1pf(__expf(a));
  }
}

// ---------------- bidirectional selective scan, LDS-staged -------------------
__global__ __launch_bounds__(256) void scan_kernel(
    const float* __restrict__ xz, const float* __restrict__ in_b,
    const float* __restrict__ dts,
    const float* __restrict__ Bsb, const float* __restrict__ Csb,
    const float* __restrict__ A_logs, const float* __restrict__ Ds,
    ushort* __restrict__ ssm)
{
  __shared__ float s_dt[3072], s_x[3072], s_B[3072], s_C[3072], s_y[3072];
  const int tid = threadIdx.x;
  const int b = blockIdx.x / 12, dblk = blockIdx.x - b * 12;
  const int d0 = dblk * 16;
  const size_t rbase = (size_t)b * 192;
  for (int i = tid; i < 768; i += 256) {
    const int l = i >> 2, j = (i & 3) << 2;
    const size_t row = rbase + l;
    ((float4*)s_dt)[i] = *(const float4*)(dts + row * 192 + d0 + j);
    const float4 xv = *(const float4*)(xz + row * 384 + d0 + j);
    const float4 bi = *(const float4*)(in_b + d0 + j);
    float4 sx; sx.x = xv.x + bi.x; sx.y = xv.y + bi.y;
    sx.z = xv.z + bi.z; sx.w = xv.w + bi.w;
    ((float4*)s_x)[i] = sx;
    ((float4*)s_B)[i] = *(const float4*)(Bsb + row * 16 + j);
    ((float4*)s_C)[i] = *(const float4*)(Csb + row * 16 + j);
  }
  __syncthreads();
  const int n = tid & 15, dl = tid >> 4;
  const float Acoef = -expf(A_logs[(d0 + dl) * 16 + n]);
  float u = 0.f;
#pragma unroll 4
  for (int l = 0; l < 192; ++l) {
    const float dt = s_dt[l * 16 + dl];
    const float c  = dt * s_B[l * 16 + n] * s_x[l * 16 + dl];
    const float a  = __expf(dt * Acoef);
    u = fmaf(a, u, c);
    float y = u * s_C[l * 16 + n];
    y += __shfl_xor(y, 1, 16); y += __shfl_xor(y, 2, 16);
    y += __shfl_xor(y, 4, 16); y += __shfl_xor(y, 8, 16);
    if (n == 0) s_y[l * 16 + dl] = y;
  }
  u = 0.f;
#pragma unroll 4
  for (int l = 191; l >= 0; --l) {
    const float dt = s_dt[l * 16 + dl];
    const float c  = dt * s_B[l * 16 + n] * s_x[l * 16 + dl];
    const float a  = __expf(dt * Acoef);
    u = fmaf(a, u, c);
    float y = u * s_C[l * 16 + n];
    y += __shfl_xor(y, 1, 16); y += __shfl_xor(y, 2, 16);
    y += __shfl_xor(y, 4, 16); y += __shfl_xor(y, 8, 16);
    if (n == 0) s_y[l * 16 + dl] += y;
  }
  __syncthreads();
  for (int i = tid; i < 768; i += 256) {
    const int l = i >> 2, j = (i & 3) << 2;
    const size_t row = rbase + l;
    const float4 y4 = ((const float4*)s_y)[i];
    const float4 x4 = ((const float4*)s_x)[i];
    const float4 zr = *(const float4*)(xz + row * 384 + 192 + d0 + j);
    const float4 bz = *(const float4*)(in_b + 192 + d0 + j);
    const float4 D4 = *(const float4*)(Ds + d0 + j);
    float4 z4; z4.x = zr.x + bz.x; z4.y = zr.y + bz.y;
    z4.z = zr.z + bz.z; z4.w = zr.w + bz.w;
    ushort4 o;
    o.x = f2bf((y4.x + 2.f * x4.x * D4.x) * (z4.x / (1.f + __expf(-z4.x))));
    o.y = f2bf((y4.y + 2.f * x4.y * D4.y) * (z4.y / (1.f + __expf(-z4.y))));
    o.z = f2bf((y4.z + 2.f * x4.z * D4.z) * (z4.z / (1.f + __expf(-z4.z))));
    o.w = f2bf((y4.w + 2.f * x4.w * D4.w) * (z4.w / (1.f + __expf(-z4.w))));
    *(ushort4*)(ssm + row * 192 + d0 + j) = o;
  }
}

// ---------------- BN prep ----------------
__global__ __launch_bounds__(64) void prep_kernel(
    const float* __restrict__ mo_w, const float* __restrict__ mo_b,
    const float* __restrict__ out_b,
    const float* __restrict__ bn_w, const float* __restrict__ bn_b,
    const float* __restrict__ bn_rm, const float* __restrict__ bn_rv,
    float* __restrict__ scale, float* __restrict__ shift)
{
  const int o = blockIdx.x, tid = threadIdx.x;
  float s = 0.f;
  for (int c = tid; c < 2048; c += 64) s = fmaf(mo_w[(size_t)o * 2048 + c], out_b[c], s);
#pragma unroll
  for (int off = 32; off > 0; off >>= 1) s += __shfl_down(s, off, 64);
  if (tid == 0) {
    const float b2 = s + mo_b[o];
    const float sc = bn_w[o] * rsqrtf(bn_rv[o] + EPSV);
    scale[o] = sc;
    shift[o] = (b2 - bn_rm[o]) * sc + bn_b[o];
  }
}

extern "C" void kernel_launch(void* const* d_in, const int* in_sizes, int n_in,
                              void* d_out, int out_size, void* d_ws, size_t ws_size,
                              hipStream_t stream) {
  const float* feat  = (const float*)d_in[0];
  const float* ln_w  = (const float*)d_in[1];
  const float* ln_b  = (const float*)d_in[2];
  const float* in_w  = (const float*)d_in[3];
  const float* in_b  = (const float*)d_in[4];
  const float* xpw   = (const float*)d_in[5];
  const float* dtw   = (const float*)d_in[6];
  const float* A_logs= (const float*)d_in[7];
  const float* Ds    = (const float*)d_in[8];
  const float* out_w = (const float*)d_in[9];
  const float* out_b = (const float*)d_in[10];
  const float* mo_w  = (const float*)d_in[11];
  const float* mo_b  = (const float*)d_in[12];
  const float* bn_w  = (const float*)d_in[13];
  const float* bn_b  = (const float*)d_in[14];
  const float* bn_rm = (const float*)d_in[15];
  const float* bn_rv = (const float*)d_in[16];
  float* out = (float*)d_out;

  // ---- workspace layout (bytes) ----
  uint8_t* p = (uint8_t*)d_ws;
  ushort* fm_b  = (ushort*)p; p += (size_t)12288 * 2048 * 2;  // 50331648
  float*  xz    = (float*)p;  p += (size_t)12288 * 384 * 4;   // 18874368
  float*  dts   = (float*)p;  p += (size_t)12288 * 192 * 4;   // 9437184
  float*  Bsb   = (float*)p;  p += (size_t)12288 * 16 * 4;    // 786432
  float*  Csb   = (float*)p;  p += (size_t)12288 * 16 * 4;    // 786432
  ushort* ssm_b = (ushort*)p; p += (size_t)12288 * 192 * 2;   // 4718592
  float*  W2f   = (float*)p;  p += (size_t)2048 * 192 * 4;    // 1572864
  ushort* W2b   = (ushort*)p; p += (size_t)2048 * 192 * 2;    // 786432
  ushort* owT_b = (ushort*)p; p += (size_t)256 * 2048 * 2;    // 1048576 (padded)
  ushort* mo_wb = (ushort*)p; p += (size_t)2048 * 2048 * 2;   // 8388608
  ushort* in_wb = (ushort*)p; p += (size_t)384 * 2048 * 2;    // 1572864
  float*  scale = (float*)p;  p += 2048 * 4;
  float*  shift = (float*)p;  p += 2048 * 4;
  float*  sums  = (float*)p;  p += (size_t)64 * 192 * 2 * 4;  // 98304
  if ((size_t)(p - (uint8_t*)d_ws) > ws_size) return;

  // weights -> bf16 (+ padded transpose of out_w)
  cvt_kernel<<<4096, 256, 0, stream>>>(mo_w, mo_wb, 2048 * 2048);
  cvt_kernel<<<768, 256, 0, stream>>>(in_w, in_wb, 384 * 2048);
  hipMemsetAsync(owT_b, 0, (size_t)256 * 2048 * 2, stream);
  transpose_w<<<dim3(32, 3), 256, 0, stream>>>(out_w, owT_b);

  // LN (stats + apply/transpose -> bf16 fm)
  hipMemsetAsync(sums, 0, (size_t)64 * 192 * 2 * 4, stream);
  ln_stats<<<dim3(64, 16), 256, 0, stream>>>(feat, sums);
  ln_apply<<<dim3(64, 32, 3), 256, 0, stream>>>(feat, sums, ln_w, ln_b, fm_b);

  // GEMM1: xz += fm @ in_w^T (split-K=4, atomic; bias folded into consumers)
  hipMemsetAsync(xz, 0, (size_t)12288 * 384 * 4, stream);
  mfma_gemm<0><<<1152, 256, 0, stream>>>(
      fm_b, in_wb, nullptr, nullptr, nullptr, nullptr, xz);

  xproj_kernel<<<3072, 256, 0, stream>>>(xz, in_b, xpw, dtw, dts, Bsb, Csb);
  scan_kernel<<<768, 256, 0, stream>>>(xz, in_b, dts, Bsb, Csb, A_logs, Ds, ssm_b);

  // W2 = mo_w @ out_w (split-K=8, atomic fp32), then bf16
  hipMemsetAsync(W2f, 0, (size_t)2048 * 192 * 4, stream);
  mfma_gemm<2><<<256, 256, 0, stream>>>(
      mo_wb, owT_b, nullptr, nullptr, nullptr, nullptr, W2f);
  cvt_kernel<<<384, 256, 0, stream>>>(W2f, W2b, 2048 * 192);
  prep_kernel<<<2048, 64, 0, stream>>>(mo_w, mo_b, out_b, bn_w, bn_b, bn_rm, bn_rv, scale, shift);

  // Final: out = relu(bn(fm@mo_w^T + ssm@W2^T)), transposed store
  mfma_gemm<1><<<1536, 256, 0, stream>>>(
      fm_b, mo_wb, ssm_b, W2b, scale, shift, out);
}